// Round 2
// baseline (258.117 us; speedup 1.0000x reference)
//
#include <hip/hip_runtime.h>

// y = x @ (W * M)^T with M = identity  =>  y[b,d] = x[b,d] * (W[d,d] * M[d,d]).
// Pure HBM-bound elementwise scale: 134 MB read + 134 MB write.
//
// Single fused kernel, no workspace, no second dispatch:
//  - grid-stride whose flat-float stride is a multiple of D=2048, so each
//    thread's column quad (d..d+3) is loop-invariant -> the 4 diagonal
//    coefficients are loaded ONCE per thread into registers, then the loop is
//    a pure load-mul-store stream.
//  - non-temporal stores for `out` (write-once, never re-read) so the 134 MB
//    of output does not evict x from L2/L3; x fits in the 256 MB Infinity
//    Cache and can stay resident across timed iterations.
//  - grid 2048 blocks x 256 thr = 8192 waves = 32 waves/CU (full occupancy),
//    16 float4 iterations per thread.
//
// NOTE: __builtin_nontemporal_store requires a clang vector type, not HIP's
// float4 struct -> use ext_vector_type(4).

#define DDIM 2048
#define BDIM 16384

typedef float floatx4 __attribute__((ext_vector_type(4)));

__global__ __launch_bounds__(256) void diag_scale_fused(
    const float* __restrict__ x,
    const float* __restrict__ W,
    const float* __restrict__ M,
    float* __restrict__ out) {
    const size_t nthreads = (size_t)gridDim.x * blockDim.x;
    const size_t t0 = (size_t)blockIdx.x * blockDim.x + threadIdx.x;
    const size_t stride4 = nthreads * 4;          // flat float stride; multiple of DDIM
    const size_t total = (size_t)BDIM * DDIM;

    // Column quad is invariant across grid-stride iterations (stride4 % DDIM == 0).
    const int d = (int)((t0 * 4) & (DDIM - 1));

    // Pull the 4 masked diagonal coefficients into registers once.
    // W[k][k] lives at flat offset k*(DDIM+1). Scattered reads but only 2048
    // distinct lines per matrix, shared by ~1024 threads each -> L2 broadcast.
    floatx4 wv;
    {
        const size_t k0 = (size_t)(d + 0) * (DDIM + 1);
        const size_t k1 = (size_t)(d + 1) * (DDIM + 1);
        const size_t k2 = (size_t)(d + 2) * (DDIM + 1);
        const size_t k3 = (size_t)(d + 3) * (DDIM + 1);
        wv.x = W[k0] * M[k0];
        wv.y = W[k1] * M[k1];
        wv.z = W[k2] * M[k2];
        wv.w = W[k3] * M[k3];
    }

    for (size_t i = t0 * 4; i < total; i += stride4) {
        floatx4 xv = *reinterpret_cast<const floatx4*>(x + i);
        floatx4 o = xv * wv;
        __builtin_nontemporal_store(o, reinterpret_cast<floatx4*>(out + i));
    }
}

extern "C" void kernel_launch(void* const* d_in, const int* in_sizes, int n_in,
                              void* d_out, int out_size, void* d_ws, size_t ws_size,
                              hipStream_t stream) {
    const float* x = (const float*)d_in[0];
    const float* W = (const float*)d_in[1];
    const float* M = (const float*)d_in[2];
    float* out = (float*)d_out;

    // 2048 blocks (even -> stride4 % DDIM == 0), 256 threads, 16 iters/thread.
    diag_scale_fused<<<2048, 256, 0, stream>>>(x, W, M, out);
}

// Round 3
// 248.130 us; speedup vs baseline: 1.0403x; 1.0403x over previous
//
#include <hip/hip_runtime.h>

// y = x @ (W * M)^T with M = identity  =>  y[b,d] = x[b,d] * (W[d,d] * M[d,d]).
// Pure HBM-bound elementwise scale: 134 MB read + 134 MB write (~45 us floor
// at the in-situ measured 6.6 TB/s fill rate).
//
// Round-2 post-mortem: fused grid-stride + nt-store ran at 2.26 TB/s with
// VGPR=12 -- the compiler didn't unroll, so each wave had ONE memory op in
// flight (load -> waitcnt -> nt store -> reg-reuse stall). Latency-bound.
//
// This version maximizes memory-level parallelism instead:
//  - each thread owns 4 float4s at the SAME column quad in 4 consecutive
//    rows: 4 independent loads + 4 independent stores, statically unrolled
//    into distinct registers -> 4-5 VMEM ops in flight per wave.
//  - the shared column quad means ONE contiguous float4 diag load per thread
//    (diag precomputed into workspace by a negligible 2048-elem kernel).
//  - plain cached stores (nt stores regressed in round 2); x (134 MB) can
//    stay L3-resident across timed iterations.

#define DDIM 2048
#define BDIM 16384

typedef float floatx4 __attribute__((ext_vector_type(4)));

// Kernel 1: pull the masked diagonal of W into contiguous workspace.
__global__ void extract_diag_kernel(const float* __restrict__ W,
                                    const float* __restrict__ M,
                                    float* __restrict__ diag) {
    int d = blockIdx.x * blockDim.x + threadIdx.x;
    if (d < DDIM) {
        size_t idx = (size_t)d * (DDIM + 1);
        diag[d] = W[idx] * M[idx];
    }
}

// Kernel 2: out[b,d] = x[b,d] * diag[d]; 4 rows x 1 float4 per thread.
__global__ __launch_bounds__(256) void diag_scale4(
    const float* __restrict__ x,
    const float* __restrict__ diag,
    float* __restrict__ out) {
    const size_t t = (size_t)blockIdx.x * blockDim.x + threadIdx.x;
    const int c4 = (int)(t & (DDIM / 4 - 1));  // float4 column index (512/row)
    const size_t rg = t >> 9;                  // row group of 4 (4096 groups)
    const size_t base = rg * 4 * DDIM + (size_t)c4 * 4;

    // One contiguous diag load, shared by all 4 rows.
    const floatx4 wv = *reinterpret_cast<const floatx4*>(diag + c4 * 4);

    // 4 independent loads -- all issued before any use.
    const floatx4 x0 = *reinterpret_cast<const floatx4*>(x + base);
    const floatx4 x1 = *reinterpret_cast<const floatx4*>(x + base + DDIM);
    const floatx4 x2 = *reinterpret_cast<const floatx4*>(x + base + 2 * DDIM);
    const floatx4 x3 = *reinterpret_cast<const floatx4*>(x + base + 3 * DDIM);

    *reinterpret_cast<floatx4*>(out + base)            = x0 * wv;
    *reinterpret_cast<floatx4*>(out + base + DDIM)     = x1 * wv;
    *reinterpret_cast<floatx4*>(out + base + 2 * DDIM) = x2 * wv;
    *reinterpret_cast<floatx4*>(out + base + 3 * DDIM) = x3 * wv;
}

extern "C" void kernel_launch(void* const* d_in, const int* in_sizes, int n_in,
                              void* d_out, int out_size, void* d_ws, size_t ws_size,
                              hipStream_t stream) {
    const float* x = (const float*)d_in[0];
    const float* W = (const float*)d_in[1];
    const float* M = (const float*)d_in[2];
    float* out = (float*)d_out;
    float* diag = (float*)d_ws;  // 2048 floats = 8 KB scratch

    extract_diag_kernel<<<(DDIM + 255) / 256, 256, 0, stream>>>(W, M, diag);

    // threads = (BDIM/4 row groups) * (DDIM/4 col quads) = 4096*512 = 2M
    const size_t total_threads = (size_t)(BDIM / 4) * (DDIM / 4);
    const int block = 256;
    const int grid = (int)(total_threads / block);  // 8192 blocks
    diag_scale4<<<grid, block, 0, stream>>>(x, diag, out);
}

// Round 4
// 239.396 us; speedup vs baseline: 1.0782x; 1.0365x over previous
//
#include <hip/hip_runtime.h>

// y = x @ (W * M)^T with M = identity  =>  y[b,d] = x[b,d] * (W[d,d] * M[d,d]).
// Pure HBM-bound elementwise scale: 134 MB read + 134 MB write.
//
// Measured history:
//  - r0: extract-diag + 1-float4/thread scale, plain stores  -> kernels ~68 us (best)
//  - r2: fused grid-stride + nt stores, compiler didn't unroll (VGPR=12)
//        -> serialized, 2.26 TB/s. BUT: FETCH_SIZE dropped to 66 MB -> nt
//        stores kept x partially L3-resident.
//  - r3: 4 rows/thread MLP variant -> ~79 us. Per-thread MLP is not the lever.
//
// This round: r0's exact shape (1-shot, no loop => nothing to serialize)
// + non-temporal stores only. out is write-once/never-read; keeping it out of
// L2/L3 leaves the Infinity Cache for x, whose reads are the latency-bound
// side of the stream.

#define DDIM 2048
#define BDIM 16384

typedef float floatx4 __attribute__((ext_vector_type(4)));

// Kernel 1: pull the masked diagonal of W into contiguous workspace.
// Strided reads (stride D+1 floats) but only 2048 of them -- negligible.
__global__ void extract_diag_kernel(const float* __restrict__ W,
                                    const float* __restrict__ M,
                                    float* __restrict__ diag) {
    int d = blockIdx.x * blockDim.x + threadIdx.x;
    if (d < DDIM) {
        size_t idx = (size_t)d * (DDIM + 1);
        diag[d] = W[idx] * M[idx];
    }
}

// Kernel 2: out[b,d] = x[b,d] * diag[d], one float4 per thread, fully
// sequential layout (block covers 4 KB contiguous; grid covers the buffer
// front-to-back). Non-temporal store for the output stream.
__global__ __launch_bounds__(256) void diag_scale_kernel(
    const float* __restrict__ x,
    const float* __restrict__ diag,
    float* __restrict__ out) {
    size_t t = (size_t)blockIdx.x * blockDim.x + threadIdx.x;
    size_t i4 = t * 4;                      // flat float index, 4 per thread
    int d = (int)(i4 & (DDIM - 1));         // column index (D power of 2)

    floatx4 xv = *reinterpret_cast<const floatx4*>(x + i4);
    floatx4 wv = *reinterpret_cast<const floatx4*>(diag + d);

    floatx4 o = xv * wv;
    __builtin_nontemporal_store(o, reinterpret_cast<floatx4*>(out + i4));
}

extern "C" void kernel_launch(void* const* d_in, const int* in_sizes, int n_in,
                              void* d_out, int out_size, void* d_ws, size_t ws_size,
                              hipStream_t stream) {
    const float* x = (const float*)d_in[0];
    const float* W = (const float*)d_in[1];
    const float* M = (const float*)d_in[2];
    float* out = (float*)d_out;
    float* diag = (float*)d_ws;  // 2048 floats = 8 KB scratch

    extract_diag_kernel<<<(DDIM + 255) / 256, 256, 0, stream>>>(W, M, diag);

    const size_t total4 = (size_t)BDIM * DDIM / 4;  // 8,388,608 float4s
    const int block = 256;
    const int grid = (int)((total4 + block - 1) / block);  // 32768 blocks
    diag_scale_kernel<<<grid, block, 0, stream>>>(x, diag, out);
}